// Round 16
// baseline (342.958 us; speedup 1.0000x reference)
//
#include <hip/hip_runtime.h>
#include <hip/hip_bf16.h>
#include <stdint.h>

// Problem constants
constexpr int NB = 2;        // batch
constexpr int NT = 4096;     // seq len
constexpr int NH = 16;       // heads
constexpr int ND = 128;      // head dim
constexpr int HID = NH * ND;         // 2048
constexpr int QKV_N = 3 * HID;       // 6144
constexpr int ROWS = NB * NT;        // 8192
constexpr int CHUNK = 32;            // scan chunk length
constexpr int NCH = NT / CHUNK;      // 128 chunks

typedef __bf16 bf16x8 __attribute__((ext_vector_type(8)));
typedef float  f32x4  __attribute__((ext_vector_type(4)));

__device__ inline unsigned short f2bf(float f) {       // RNE fp32->bf16
    unsigned u = __builtin_bit_cast(unsigned, f);
    u += 0x7fffu + ((u >> 16) & 1u);
    return (unsigned short)(u >> 16);
}
__device__ inline float bf2f(unsigned short b) {
    unsigned u = ((unsigned)b) << 16;
    return __builtin_bit_cast(float, u);
}

// ---------- fused prep: cast x AND transpose both weights (1 launch) ------
constexpr int PREP_CAST_BLK = 2048;
constexpr int PREP_TQ_BLK   = (QKV_N / 32) * (HID / 32);   // 12288
constexpr int PREP_TW_BLK   = (HID / 32) * (HID / 32);     // 4096

__global__ __launch_bounds__(256) void prep_kernel(
        const float* __restrict__ x, const float* __restrict__ w_qkv,
        const float* __restrict__ w_out,
        unsigned short* __restrict__ xb, unsigned short* __restrict__ wqkvT,
        unsigned short* __restrict__ woutT) {
    __shared__ float tile[32][33];
    const int b = blockIdx.x;
    if (b < PREP_CAST_BLK) {
        size_t n4 = (size_t)ROWS * HID / 4;
        size_t i = b * (size_t)blockDim.x + threadIdx.x;
        size_t stride = (size_t)PREP_CAST_BLK * blockDim.x;
        for (; i < n4; i += stride) {
            float4 v = reinterpret_cast<const float4*>(x)[i];
            ushort4 o;
            o.x = f2bf(v.x); o.y = f2bf(v.y); o.z = f2bf(v.z); o.w = f2bf(v.w);
            reinterpret_cast<ushort4*>(xb)[i] = o;
        }
        return;
    }
    const float* in;
    unsigned short* out;
    int R, Cn, tb;
    if (b < PREP_CAST_BLK + PREP_TQ_BLK) {
        tb = b - PREP_CAST_BLK; in = w_qkv; out = wqkvT; R = HID; Cn = QKV_N;
    } else {
        tb = b - PREP_CAST_BLK - PREP_TQ_BLK; in = w_out; out = woutT; R = HID; Cn = HID;
    }
    const int nbx = Cn / 32;
    const int c0 = (tb % nbx) * 32, r0 = (tb / nbx) * 32;
    const int c  = threadIdx.x & 31;
    const int r8 = threadIdx.x >> 5;          // 0..7
    #pragma unroll
    for (int i = 0; i < 32; i += 8)
        tile[r8 + i][c] = in[(size_t)(r0 + r8 + i) * Cn + c0 + c];
    __syncthreads();
    #pragma unroll
    for (int i = 0; i < 32; i += 8)
        out[(size_t)(c0 + r8 + i) * R + r0 + c] = f2bf(tile[c][r8 + i]);
}

// ====== 256x128 4-wave(128x64) BK=32 double-buffered GEMM ==================
// Round 16: fatter per-wave tiles to cut LDS-read bytes per FLOP (the
// measured limiter: ds_read_b128 ~85 B/cy/CU). 12 ds_read_b128 per 32 MFMA
// per wave-step vs r10's 16 per 32 -> 1.33x read-ratio. LDS 48 KiB;
// registers (acc[8][4]=128) cap occupancy at 2 blocks/CU (same TLP as r10).
// BK=32 swizzle fixed at 16-lane-group granularity: slot = ko ^ ((row>>1)&3)
// (r12's ko^(row&3) left quarter-waves on 4/8 granule groups -> conflicts).

__device__ __forceinline__ void gll(const unsigned short* src, unsigned short* dst) {
    __builtin_amdgcn_global_load_lds(
        (const __attribute__((address_space(1))) void*)src,
        (__attribute__((address_space(3))) void*)dst, 16, 0, 0);
}

// Stage a [R x 32] bf16 tile: each round, 4 waves cover 64 rows (16/wave);
// lane l -> row rbase+(l>>2), slot l&3; source ko = (l&3) ^ ((row>>1)&3).
template <int NROUND>
__device__ __forceinline__ void stage_t(const unsigned short* G, int K, int k0,
                                        unsigned short* lds, int wid, int lane) {
    const int rl = lane >> 2;                        // 0..15 row within group
    #pragma unroll
    for (int j = 0; j < NROUND; ++j) {
        int rbase = wid * 16 + j * 64;
        int row = rbase + rl;
        int ce = ((lane & 3) ^ ((row >> 1) & 3)) * 8;   // inverse-swizzled col
        gll(G + (size_t)row * K + k0 + ce, lds + rbase * 32);
    }
}

// swizzled ds_read: row r, k-octet fq; slot = fq ^ ((r>>1)&3)
__device__ __forceinline__ bf16x8 ld_frag(const unsigned short* tile,
                                          int r, int fq) {
    int slot = fq ^ ((r >> 1) & 3);
    return *reinterpret_cast<const bf16x8*>(tile + r * 32 + slot * 8);
}

template <typename OUT_T>
__global__ __launch_bounds__(256, 2) void gemm256x128(
        const unsigned short* __restrict__ A,   // [M][K] bf16
        const unsigned short* __restrict__ Bt,  // [N][K] bf16
        OUT_T* __restrict__ C,                  // [M][N]
        int M, int N, int K, int byc) {
    __shared__ unsigned short As0[256 * 32];
    __shared__ unsigned short As1[256 * 32];
    __shared__ unsigned short Bs0[128 * 32];
    __shared__ unsigned short Bs1[128 * 32];

    const int bid = blockIdx.x;
    const int xcd = bid & 7;
    const int c   = bid >> 3;
    const int by  = xcd * byc + (c % byc);   // byc-wide by-band per XCD
    const int bx  = c / byc;                 // column-major within band
    const int tid = threadIdx.x, wid = tid >> 6, lane = tid & 63;
    const int wm  = wid >> 1, wn = wid & 1;  // 2x2 waves, 128x64 each
    const int fr  = lane & 15, fq = lane >> 4;

    const unsigned short* Ag = A  + (size_t)by * 256 * K;
    const unsigned short* Bg = Bt + (size_t)bx * 128 * K;

    f32x4 acc[8][4] = {};

    stage_t<4>(Ag, K, 0, As0, wid, lane);
    stage_t<2>(Bg, K, 0, Bs0, wid, lane);
    __syncthreads();

    const int NK = K / 32;
    for (int t = 0; t < NK; ++t) {
        const unsigned short* Ac = (t & 1) ? As1 : As0;
        const unsigned short* Bc = (t & 1) ? Bs1 : Bs0;
        if (t + 1 < NK) {   // prefetch next K-tile into the other buffer
            unsigned short* An = (t & 1) ? As0 : As1;
            unsigned short* Bn = (t & 1) ? Bs0 : Bs1;
            stage_t<4>(Ag, K, (t + 1) * 32, An, wid, lane);
            stage_t<2>(Bg, K, (t + 1) * 32, Bn, wid, lane);
        }
        bf16x8 af[8], bf[4];
        #pragma unroll
        for (int m = 0; m < 8; ++m)
            af[m] = ld_frag(Ac, wm * 128 + m * 16 + fr, fq);
        #pragma unroll
        for (int n = 0; n < 4; ++n)
            bf[n] = ld_frag(Bc, wn * 64 + n * 16 + fr, fq);
        __builtin_amdgcn_s_setprio(1);
        #pragma unroll
        for (int m = 0; m < 8; ++m)
            #pragma unroll
            for (int n = 0; n < 4; ++n)
                acc[m][n] = __builtin_amdgcn_mfma_f32_16x16x32_bf16(
                    af[m], bf[n], acc[m][n], 0, 0, 0);
        __builtin_amdgcn_s_setprio(0);
        __syncthreads();
    }

    // C write (verified C/D layout: row = fq*4+r, col = fr)
    const int bm = by * 256, bn = bx * 128;
    #pragma unroll
    for (int m = 0; m < 8; ++m) {
        #pragma unroll
        for (int n = 0; n < 4; ++n) {
            #pragma unroll
            for (int r = 0; r < 4; ++r) {
                int row = bm + wm * 128 + m * 16 + fq * 4 + r;
                int col = bn + wn * 64 + n * 16 + fr;
                float v = acc[m][n][r];
                if constexpr (sizeof(OUT_T) == 2)
                    C[(size_t)row * N + col] = (OUT_T)f2bf(v);
                else
                    C[(size_t)row * N + col] = (OUT_T)v;
            }
        }
    }
}

// ---------------- scan helpers ----------------
__device__ inline float phi_f(float z) { return z > 0.f ? z + 1.f : __expf(z); }
__device__ inline float sigmoid_f(float z) { return 1.f / (1.f + __expf(-z)); }

// Pass 1: per-(b,h,chunk) local scan finals (zero init). qkv bf16.
__global__ void scan_pass1(const unsigned short* __restrict__ qkv,
                           const float* __restrict__ decay_param,
                           float* __restrict__ fkv, float* __restrict__ fk) {
    const int blk = blockIdx.x;
    const int c = blk % NCH;
    const int h = (blk / NCH) % NH;
    const int b = blk / (NCH * NH);
    const int lane = threadIdx.x;
    const float dec = sigmoid_f(decay_param[h]);

    float skv0 = 0.f, skv1 = 0.f, sk0 = 0.f, sk1 = 0.f;
    const unsigned short* base =
        qkv + ((size_t)b * NT + (size_t)c * CHUNK) * QKV_N + h * ND;
    for (int t = 0; t < CHUNK; ++t) {
        const unsigned short* r = base + (size_t)t * QKV_N;
        unsigned kp = *reinterpret_cast<const unsigned*>(r + HID + 2 * lane);
        unsigned vp = *reinterpret_cast<const unsigned*>(r + 2 * HID + 2 * lane);
        float k0 = phi_f(bf2f((unsigned short)(kp & 0xffff)));
        float k1 = phi_f(bf2f((unsigned short)(kp >> 16)));
        float v0 = bf2f((unsigned short)(vp & 0xffff));
        float v1 = bf2f((unsigned short)(vp >> 16));
        skv0 = fmaf(dec, skv0, k0 * v0);
        skv1 = fmaf(dec, skv1, k1 * v1);
        sk0  = fmaf(dec, sk0,  k0);
        sk1  = fmaf(dec, sk1,  k1);
    }
    size_t o = (size_t)blk * ND + 2 * lane;
    *reinterpret_cast<float2*>(&fkv[o]) = make_float2(skv0, skv1);
    *reinterpret_cast<float2*>(&fk[o])  = make_float2(sk0, sk1);
}

// Pass 2: sequential chunk combine; emits carry-ins and final states.
__global__ void scan_pass2(const float* __restrict__ fkv, const float* __restrict__ fk,
                           const float* __restrict__ decay_param,
                           float* __restrict__ ckv, float* __restrict__ ck,
                           float* __restrict__ out_states) {
    const int bh = blockIdx.x;
    const int h = bh % NH;
    const int lane = threadIdx.x;
    const float dec = sigmoid_f(decay_param[h]);
    const float dL = powf(dec, (float)CHUNK);

    float Skv0 = 0.f, Skv1 = 0.f, Sk0 = 0.f, Sk1 = 0.f;
    for (int c = 0; c < NCH; ++c) {
        size_t o = ((size_t)bh * NCH + c) * ND + 2 * lane;
        *reinterpret_cast<float2*>(&ckv[o]) = make_float2(Skv0, Skv1);
        *reinterpret_cast<float2*>(&ck[o])  = make_float2(Sk0, Sk1);
        float2 fv = *reinterpret_cast<const float2*>(&fkv[o]);
        float2 fs = *reinterpret_cast<const float2*>(&fk[o]);
        Skv0 = fmaf(dL, Skv0, fv.x);
        Skv1 = fmaf(dL, Skv1, fv.y);
        Sk0  = fmaf(dL, Sk0,  fs.x);
        Sk1  = fmaf(dL, Sk1,  fs.y);
    }
    size_t so = (size_t)bh * ND + 2 * lane;
    *reinterpret_cast<float2*>(&out_states[so]) = make_float2(Skv0, Skv1);
    *reinterpret_cast<float2*>(&out_states[NB * NH * ND + so]) = make_float2(Sk0, Sk1);
}

// Pass 3: replay with carry-in; writes attn in bf16.
__global__ void scan_pass3(const unsigned short* __restrict__ qkv,
                           const float* __restrict__ decay_param,
                           const float* __restrict__ ckv, const float* __restrict__ ck,
                           unsigned short* __restrict__ attn) {
    const int blk = blockIdx.x;
    const int c = blk % NCH;
    const int h = (blk / NCH) % NH;
    const int b = blk / (NCH * NH);
    const int lane = threadIdx.x;
    const float dec = sigmoid_f(decay_param[h]);

    size_t co = (size_t)blk * ND + 2 * lane;
    float2 cv = *reinterpret_cast<const float2*>(&ckv[co]);
    float2 cs = *reinterpret_cast<const float2*>(&ck[co]);
    float skv0 = cv.x, skv1 = cv.y, sk0 = cs.x, sk1 = cs.y;

    const unsigned short* base =
        qkv + ((size_t)b * NT + (size_t)c * CHUNK) * QKV_N + h * ND;
    unsigned short* abase =
        attn + ((size_t)b * NT + (size_t)c * CHUNK) * HID + h * ND;

    for (int t = 0; t < CHUNK; ++t) {
        const unsigned short* r = base + (size_t)t * QKV_N;
        unsigned qp = *reinterpret_cast<const unsigned*>(r + 2 * lane);
        unsigned kp = *reinterpret_cast<const unsigned*>(r + HID + 2 * lane);
        unsigned vp = *reinterpret_cast<const unsigned*>(r + 2 * HID + 2 * lane);
        float q0 = phi_f(bf2f((unsigned short)(qp & 0xffff)));
        float q1 = phi_f(bf2f((unsigned short)(qp >> 16)));
        float k0 = phi_f(bf2f((unsigned short)(kp & 0xffff)));
        float k1 = phi_f(bf2f((unsigned short)(kp >> 16)));
        float v0 = bf2f((unsigned short)(vp & 0xffff));
        float v1 = bf2f((unsigned short)(vp >> 16));
        skv0 = fmaf(dec, skv0, k0 * v0);
        skv1 = fmaf(dec, skv1, k1 * v1);
        sk0  = fmaf(dec, sk0,  k0);
        sk1  = fmaf(dec, sk1,  k1);
        float den = fmaf(q0, sk0, q1 * sk1);
        #pragma unroll
        for (int m = 1; m < 64; m <<= 1) den += __shfl_xor(den, m, 64);
        den = fmaxf(den, 1e-6f);
        float inv = 1.f / den;
        unsigned o = ((unsigned)f2bf(q1 * skv1 * inv) << 16) |
                     (unsigned)f2bf(q0 * skv0 * inv);
        *reinterpret_cast<unsigned*>(abase + (size_t)t * HID + 2 * lane) = o;
    }
}

// ---------------- launch ----------------
extern "C" void kernel_launch(void* const* d_in, const int* in_sizes, int n_in,
                              void* d_out, int out_size, void* d_ws, size_t ws_size,
                              hipStream_t stream) {
    const float* x      = (const float*)d_in[0];   // [2,4096,2048]
    const float* w_qkv  = (const float*)d_in[1];   // [2048,6144]
    const float* w_out  = (const float*)d_in[2];   // [2048,2048]
    const float* decayp = (const float*)d_in[3];   // [16]
    float* out = (float*)d_out;

    // workspace layout
    char* ws = (char*)d_ws;
    unsigned short* xb     = (unsigned short*)ws;                         // 8192*2048
    unsigned short* wqkvT  = xb    + (size_t)ROWS * HID;                  // 6144*2048
    unsigned short* woutT  = wqkvT + (size_t)QKV_N * HID;                 // 2048*2048
    unsigned short* qkvb   = woutT + (size_t)HID * HID;                   // 8192*6144
    unsigned short* attnb  = qkvb  + (size_t)ROWS * QKV_N;                // 8192*2048
    float* fkv = (float*)(attnb + (size_t)ROWS * HID);
    float* fk  = fkv + (size_t)NB * NH * NCH * ND;
    float* ckv = fk  + (size_t)NB * NH * NCH * ND;
    float* ck  = ckv + (size_t)NB * NH * NCH * ND;

    // fused prep: cast x + transpose both weights (1 launch)
    prep_kernel<<<PREP_CAST_BLK + PREP_TQ_BLK + PREP_TW_BLK, 256, 0, stream>>>(
        x, w_qkv, w_out, xb, wqkvT, woutT);

    // GEMM1: qkvb = xb @ wqkvT^T   (bf16 out)  grid 32x48 = 1536 blocks
    {
        int nby = ROWS / 256, nbx = QKV_N / 128;
        gemm256x128<unsigned short><<<nby * nbx, 256, 0, stream>>>(
            xb, wqkvT, qkvb, ROWS, QKV_N, HID, nby / 8);
    }

    // chunked decay scans (CHUNK=32 -> 4096 blocks)
    scan_pass1<<<NB * NH * NCH, 64, 0, stream>>>(qkvb, decayp, fkv, fk);
    scan_pass2<<<NB * NH, 64, 0, stream>>>(fkv, fk, decayp, ckv, ck,
                                           out + (size_t)ROWS * HID);
    scan_pass3<<<NB * NH * NCH, 64, 0, stream>>>(qkvb, decayp, ckv, ck, attnb);

    // GEMM2: out = attnb @ woutT^T  (f32 out)  grid 32x16 = 512 blocks
    {
        int nby = ROWS / 256, nbx = HID / 128;
        gemm256x128<float><<<nby * nbx, 256, 0, stream>>>(
            attnb, woutT, out, ROWS, HID, HID, nby / 8);
    }
}

// Round 17
// 335.637 us; speedup vs baseline: 1.0218x; 1.0218x over previous
//
#include <hip/hip_runtime.h>
#include <hip/hip_bf16.h>
#include <stdint.h>

// Problem constants
constexpr int NB = 2;        // batch
constexpr int NT = 4096;     // seq len
constexpr int NH = 16;       // heads
constexpr int ND = 128;      // head dim
constexpr int HID = NH * ND;         // 2048
constexpr int QKV_N = 3 * HID;       // 6144
constexpr int ROWS = NB * NT;        // 8192
constexpr int CHUNK = 16;            // scan chunk length (r17: 32->16)
constexpr int NCH = NT / CHUNK;      // 256 chunks

typedef __bf16 bf16x8 __attribute__((ext_vector_type(8)));
typedef float  f32x4  __attribute__((ext_vector_type(4)));

__device__ inline unsigned short f2bf(float f) {       // RNE fp32->bf16
    unsigned u = __builtin_bit_cast(unsigned, f);
    u += 0x7fffu + ((u >> 16) & 1u);
    return (unsigned short)(u >> 16);
}
__device__ inline float bf2f(unsigned short b) {
    unsigned u = ((unsigned)b) << 16;
    return __builtin_bit_cast(float, u);
}

// ---------- fused prep: cast x AND transpose both weights (1 launch) ------
constexpr int PREP_CAST_BLK = 2048;
constexpr int PREP_TQ_BLK   = (QKV_N / 32) * (HID / 32);   // 12288
constexpr int PREP_TW_BLK   = (HID / 32) * (HID / 32);     // 4096

__global__ __launch_bounds__(256) void prep_kernel(
        const float* __restrict__ x, const float* __restrict__ w_qkv,
        const float* __restrict__ w_out,
        unsigned short* __restrict__ xb, unsigned short* __restrict__ wqkvT,
        unsigned short* __restrict__ woutT) {
    __shared__ float tile[32][33];
    const int b = blockIdx.x;
    if (b < PREP_CAST_BLK) {
        size_t n4 = (size_t)ROWS * HID / 4;
        size_t i = b * (size_t)blockDim.x + threadIdx.x;
        size_t stride = (size_t)PREP_CAST_BLK * blockDim.x;
        for (; i < n4; i += stride) {
            float4 v = reinterpret_cast<const float4*>(x)[i];
            ushort4 o;
            o.x = f2bf(v.x); o.y = f2bf(v.y); o.z = f2bf(v.z); o.w = f2bf(v.w);
            reinterpret_cast<ushort4*>(xb)[i] = o;
        }
        return;
    }
    const float* in;
    unsigned short* out;
    int R, Cn, tb;
    if (b < PREP_CAST_BLK + PREP_TQ_BLK) {
        tb = b - PREP_CAST_BLK; in = w_qkv; out = wqkvT; R = HID; Cn = QKV_N;
    } else {
        tb = b - PREP_CAST_BLK - PREP_TQ_BLK; in = w_out; out = woutT; R = HID; Cn = HID;
    }
    const int nbx = Cn / 32;
    const int c0 = (tb % nbx) * 32, r0 = (tb / nbx) * 32;
    const int c  = threadIdx.x & 31;
    const int r8 = threadIdx.x >> 5;          // 0..7
    #pragma unroll
    for (int i = 0; i < 32; i += 8)
        tile[r8 + i][c] = in[(size_t)(r0 + r8 + i) * Cn + c0 + c];
    __syncthreads();
    #pragma unroll
    for (int i = 0; i < 32; i += 8)
        out[(size_t)(c0 + r8 + i) * R + r0 + c] = f2bf(tile[c][r8 + i]);
}

// ====== 128x128 4-wave BK=64 double-buffered GEMM, 2 blocks/CU =============
// Final config (r10/r14/r15, reproduced 3x): 191 µs GEMM1, MfmaUtil 52-53%,
// FETCH 197 MB, conflicts 0. XCD 2D-window mapping + 2 barrier domains.
// Mapped neighborhood (all worse): 8-phase 1-blk (r4-r8), 8-wave same-domain
// (r11), BK=32 (r12/r16), B-direct (r13), 256x128 fat-wave (r16).

__device__ __forceinline__ void gll(const unsigned short* src, unsigned short* dst) {
    __builtin_amdgcn_global_load_lds(
        (const __attribute__((address_space(1))) void*)src,
        (__attribute__((address_space(3))) void*)dst, 16, 0, 0);
}

// Stage one 128x64 bf16 tile (16 KB): 4 waves x 4 rounds x 8 rows.
__device__ __forceinline__ void stage_t(const unsigned short* G, int K, int k0,
                                        unsigned short* lds, int wid, int lane) {
    const int rbase = wid * 32;
    const int rl = lane >> 3;                        // 0..7 row within group
    const int ce = ((lane & 7) ^ rl) * 8;            // inverse-swizzled col
    #pragma unroll
    for (int j = 0; j < 4; ++j) {
        gll(G + (size_t)(rbase + j * 8 + rl) * K + k0 + ce,
            lds + (rbase + j * 8) * 64);
    }
}

// swizzled ds_read: row r, k-slot kk*4+fq (8 slots of 8 bf16 across BK=64)
__device__ __forceinline__ bf16x8 ld_frag(const unsigned short* tile,
                                          int r, int kk, int fq) {
    int slot = (kk * 4 + fq) ^ (r & 7);
    return *reinterpret_cast<const bf16x8*>(tile + r * 64 + slot * 8);
}

template <typename OUT_T>
__global__ __launch_bounds__(256, 2) void gemm128(
        const unsigned short* __restrict__ A,   // [M][K] bf16
        const unsigned short* __restrict__ Bt,  // [N][K] bf16
        OUT_T* __restrict__ C,                  // [M][N]
        int M, int N, int K, int byc) {
    __shared__ unsigned short As0[128 * 64];
    __shared__ unsigned short As1[128 * 64];
    __shared__ unsigned short Bs0[128 * 64];
    __shared__ unsigned short Bs1[128 * 64];

    const int bid = blockIdx.x;
    const int xcd = bid & 7;
    const int c   = bid >> 3;
    const int by  = xcd * byc + (c % byc);   // 8-wide by-band per XCD
    const int bx  = c / byc;                 // column-major within band
    const int tid = threadIdx.x, wid = tid >> 6, lane = tid & 63;
    const int wm  = wid >> 1, wn = wid & 1;         // 2x2 waves, 64x64 each
    const int fr  = lane & 15, fq = lane >> 4;

    const unsigned short* Ag = A  + (size_t)by * 128 * K;
    const unsigned short* Bg = Bt + (size_t)bx * 128 * K;

    f32x4 acc[4][4] = {};

    stage_t(Ag, K, 0, As0, wid, lane);
    stage_t(Bg, K, 0, Bs0, wid, lane);
    __syncthreads();

    const int NK = K / 64;
    for (int t = 0; t < NK; ++t) {
        const unsigned short* Ac = (t & 1) ? As1 : As0;
        const unsigned short* Bc = (t & 1) ? Bs1 : Bs0;
        if (t + 1 < NK) {   // prefetch next K-tile into the other buffer
            unsigned short* An = (t & 1) ? As0 : As1;
            unsigned short* Bn = (t & 1) ? Bs0 : Bs1;
            stage_t(Ag, K, (t + 1) * 64, An, wid, lane);
            stage_t(Bg, K, (t + 1) * 64, Bn, wid, lane);
        }
        bf16x8 af[4][2], bf[4][2];
        #pragma unroll
        for (int m = 0; m < 4; ++m) {
            int r = wm * 64 + m * 16 + fr;
            af[m][0] = ld_frag(Ac, r, 0, fq);
            af[m][1] = ld_frag(Ac, r, 1, fq);
        }
        #pragma unroll
        for (int n = 0; n < 4; ++n) {
            int r = wn * 64 + n * 16 + fr;
            bf[n][0] = ld_frag(Bc, r, 0, fq);
            bf[n][1] = ld_frag(Bc, r, 1, fq);
        }
        __builtin_amdgcn_s_setprio(1);
        #pragma unroll
        for (int kk = 0; kk < 2; ++kk)
            #pragma unroll
            for (int m = 0; m < 4; ++m)
                #pragma unroll
                for (int n = 0; n < 4; ++n)
                    acc[m][n] = __builtin_amdgcn_mfma_f32_16x16x32_bf16(
                        af[m][kk], bf[n][kk], acc[m][n], 0, 0, 0);
        __builtin_amdgcn_s_setprio(0);
        __syncthreads();
    }

    // C write (verified C/D layout: row = fq*4+r, col = fr)
    const int bm = by * 128, bn = bx * 128;
    #pragma unroll
    for (int m = 0; m < 4; ++m) {
        #pragma unroll
        for (int n = 0; n < 4; ++n) {
            #pragma unroll
            for (int r = 0; r < 4; ++r) {
                int row = bm + wm * 64 + m * 16 + fq * 4 + r;
                int col = bn + wn * 64 + n * 16 + fr;
                float v = acc[m][n][r];
                if constexpr (sizeof(OUT_T) == 2)
                    C[(size_t)row * N + col] = (OUT_T)f2bf(v);
                else
                    C[(size_t)row * N + col] = (OUT_T)v;
            }
        }
    }
}

// ---------------- scan helpers ----------------
__device__ inline float phi_f(float z) { return z > 0.f ? z + 1.f : __expf(z); }
__device__ inline float sigmoid_f(float z) { return 1.f / (1.f + __expf(-z)); }

// Pass 1: per-(b,h,chunk) local scan finals (zero init). qkv bf16.
// r17: CHUNK=16 -> 8192 blocks (32 waves/CU) to hide load latency.
__global__ void scan_pass1(const unsigned short* __restrict__ qkv,
                           const float* __restrict__ decay_param,
                           float* __restrict__ fkv, float* __restrict__ fk) {
    const int blk = blockIdx.x;
    const int c = blk % NCH;
    const int h = (blk / NCH) % NH;
    const int b = blk / (NCH * NH);
    const int lane = threadIdx.x;
    const float dec = sigmoid_f(decay_param[h]);

    float skv0 = 0.f, skv1 = 0.f, sk0 = 0.f, sk1 = 0.f;
    const unsigned short* base =
        qkv + ((size_t)b * NT + (size_t)c * CHUNK) * QKV_N + h * ND;
    for (int t = 0; t < CHUNK; ++t) {
        const unsigned short* r = base + (size_t)t * QKV_N;
        unsigned kp = *reinterpret_cast<const unsigned*>(r + HID + 2 * lane);
        unsigned vp = *reinterpret_cast<const unsigned*>(r + 2 * HID + 2 * lane);
        float k0 = phi_f(bf2f((unsigned short)(kp & 0xffff)));
        float k1 = phi_f(bf2f((unsigned short)(kp >> 16)));
        float v0 = bf2f((unsigned short)(vp & 0xffff));
        float v1 = bf2f((unsigned short)(vp >> 16));
        skv0 = fmaf(dec, skv0, k0 * v0);
        skv1 = fmaf(dec, skv1, k1 * v1);
        sk0  = fmaf(dec, sk0,  k0);
        sk1  = fmaf(dec, sk1,  k1);
    }
    size_t o = (size_t)blk * ND + 2 * lane;
    *reinterpret_cast<float2*>(&fkv[o]) = make_float2(skv0, skv1);
    *reinterpret_cast<float2*>(&fk[o])  = make_float2(sk0, sk1);
}

// Pass 2: sequential chunk combine; emits carry-ins and final states.
__global__ void scan_pass2(const float* __restrict__ fkv, const float* __restrict__ fk,
                           const float* __restrict__ decay_param,
                           float* __restrict__ ckv, float* __restrict__ ck,
                           float* __restrict__ out_states) {
    const int bh = blockIdx.x;
    const int h = bh % NH;
    const int lane = threadIdx.x;
    const float dec = sigmoid_f(decay_param[h]);
    const float dL = powf(dec, (float)CHUNK);

    float Skv0 = 0.f, Skv1 = 0.f, Sk0 = 0.f, Sk1 = 0.f;
    for (int c = 0; c < NCH; ++c) {
        size_t o = ((size_t)bh * NCH + c) * ND + 2 * lane;
        *reinterpret_cast<float2*>(&ckv[o]) = make_float2(Skv0, Skv1);
        *reinterpret_cast<float2*>(&ck[o])  = make_float2(Sk0, Sk1);
        float2 fv = *reinterpret_cast<const float2*>(&fkv[o]);
        float2 fs = *reinterpret_cast<const float2*>(&fk[o]);
        Skv0 = fmaf(dL, Skv0, fv.x);
        Skv1 = fmaf(dL, Skv1, fv.y);
        Sk0  = fmaf(dL, Sk0,  fs.x);
        Sk1  = fmaf(dL, Sk1,  fs.y);
    }
    size_t so = (size_t)bh * ND + 2 * lane;
    *reinterpret_cast<float2*>(&out_states[so]) = make_float2(Skv0, Skv1);
    *reinterpret_cast<float2*>(&out_states[NB * NH * ND + so]) = make_float2(Sk0, Sk1);
}

// Pass 3: replay with carry-in; writes attn in bf16.
__global__ void scan_pass3(const unsigned short* __restrict__ qkv,
                           const float* __restrict__ decay_param,
                           const float* __restrict__ ckv, const float* __restrict__ ck,
                           unsigned short* __restrict__ attn) {
    const int blk = blockIdx.x;
    const int c = blk % NCH;
    const int h = (blk / NCH) % NH;
    const int b = blk / (NCH * NH);
    const int lane = threadIdx.x;
    const float dec = sigmoid_f(decay_param[h]);

    size_t co = (size_t)blk * ND + 2 * lane;
    float2 cv = *reinterpret_cast<const float2*>(&ckv[co]);
    float2 cs = *reinterpret_cast<const float2*>(&ck[co]);
    float skv0 = cv.x, skv1 = cv.y, sk0 = cs.x, sk1 = cs.y;

    const unsigned short* base =
        qkv + ((size_t)b * NT + (size_t)c * CHUNK) * QKV_N + h * ND;
    unsigned short* abase =
        attn + ((size_t)b * NT + (size_t)c * CHUNK) * HID + h * ND;

    for (int t = 0; t < CHUNK; ++t) {
        const unsigned short* r = base + (size_t)t * QKV_N;
        unsigned qp = *reinterpret_cast<const unsigned*>(r + 2 * lane);
        unsigned kp = *reinterpret_cast<const unsigned*>(r + HID + 2 * lane);
        unsigned vp = *reinterpret_cast<const unsigned*>(r + 2 * HID + 2 * lane);
        float q0 = phi_f(bf2f((unsigned short)(qp & 0xffff)));
        float q1 = phi_f(bf2f((unsigned short)(qp >> 16)));
        float k0 = phi_f(bf2f((unsigned short)(kp & 0xffff)));
        float k1 = phi_f(bf2f((unsigned short)(kp >> 16)));
        float v0 = bf2f((unsigned short)(vp & 0xffff));
        float v1 = bf2f((unsigned short)(vp >> 16));
        skv0 = fmaf(dec, skv0, k0 * v0);
        skv1 = fmaf(dec, skv1, k1 * v1);
        sk0  = fmaf(dec, sk0,  k0);
        sk1  = fmaf(dec, sk1,  k1);
        float den = fmaf(q0, sk0, q1 * sk1);
        #pragma unroll
        for (int m = 1; m < 64; m <<= 1) den += __shfl_xor(den, m, 64);
        den = fmaxf(den, 1e-6f);
        float inv = 1.f / den;
        unsigned o = ((unsigned)f2bf(q1 * skv1 * inv) << 16) |
                     (unsigned)f2bf(q0 * skv0 * inv);
        *reinterpret_cast<unsigned*>(abase + (size_t)t * HID + 2 * lane) = o;
    }
}

// ---------------- launch ----------------
extern "C" void kernel_launch(void* const* d_in, const int* in_sizes, int n_in,
                              void* d_out, int out_size, void* d_ws, size_t ws_size,
                              hipStream_t stream) {
    const float* x      = (const float*)d_in[0];   // [2,4096,2048]
    const float* w_qkv  = (const float*)d_in[1];   // [2048,6144]
    const float* w_out  = (const float*)d_in[2];   // [2048,2048]
    const float* decayp = (const float*)d_in[3];   // [16]
    float* out = (float*)d_out;

    // workspace layout
    char* ws = (char*)d_ws;
    unsigned short* xb     = (unsigned short*)ws;                         // 8192*2048
    unsigned short* wqkvT  = xb    + (size_t)ROWS * HID;                  // 6144*2048
    unsigned short* woutT  = wqkvT + (size_t)QKV_N * HID;                 // 2048*2048
    unsigned short* qkvb   = woutT + (size_t)HID * HID;                   // 8192*6144
    unsigned short* attnb  = qkvb  + (size_t)ROWS * QKV_N;                // 8192*2048
    float* fkv = (float*)(attnb + (size_t)ROWS * HID);
    float* fk  = fkv + (size_t)NB * NH * NCH * ND;
    float* ckv = fk  + (size_t)NB * NH * NCH * ND;
    float* ck  = ckv + (size_t)NB * NH * NCH * ND;

    // fused prep: cast x + transpose both weights (1 launch)
    prep_kernel<<<PREP_CAST_BLK + PREP_TQ_BLK + PREP_TW_BLK, 256, 0, stream>>>(
        x, w_qkv, w_out, xb, wqkvT, woutT);

    // GEMM1: qkvb = xb @ wqkvT^T   (bf16 out)  grid 64x48 = 3072 blocks
    {
        int nby = ROWS / 128, nbx = QKV_N / 128;
        gemm128<unsigned short><<<nby * nbx, 256, 0, stream>>>(
            xb, wqkvT, qkvb, ROWS, QKV_N, HID, nby / 8);
    }

    // chunked decay scans (CHUNK=16 -> 8192 blocks, 32 waves/CU)
    scan_pass1<<<NB * NH * NCH, 64, 0, stream>>>(qkvb, decayp, fkv, fk);
    scan_pass2<<<NB * NH, 64, 0, stream>>>(fkv, fk, decayp, ckv, ck,
                                           out + (size_t)ROWS * HID);
    scan_pass3<<<NB * NH * NCH, 64, 0, stream>>>(qkvb, decayp, ckv, ck, attnb);

    // GEMM2: out = attnb @ woutT^T  (f32 out)  grid 64x16 = 1024 blocks
    {
        int nby = ROWS / 128, nbx = HID / 128;
        gemm128<float><<<nby * nbx, 256, 0, stream>>>(
            attnb, woutT, out, ROWS, HID, HID, nby / 8);
    }
}

// Round 18
// 332.887 us; speedup vs baseline: 1.0303x; 1.0083x over previous
//
#include <hip/hip_runtime.h>
#include <hip/hip_bf16.h>
#include <stdint.h>

// Problem constants
constexpr int NB = 2;        // batch
constexpr int NT = 4096;     // seq len
constexpr int NH = 16;       // heads
constexpr int ND = 128;      // head dim
constexpr int HID = NH * ND;         // 2048
constexpr int QKV_N = 3 * HID;       // 6144
constexpr int ROWS = NB * NT;        // 8192
constexpr int CHUNK = 32;            // scan chunk length (best: r15)
constexpr int NCH = NT / CHUNK;      // 128 chunks

typedef __bf16 bf16x8 __attribute__((ext_vector_type(8)));
typedef float  f32x4  __attribute__((ext_vector_type(4)));

__device__ inline unsigned short f2bf(float f) {       // RNE fp32->bf16
    unsigned u = __builtin_bit_cast(unsigned, f);
    u += 0x7fffu + ((u >> 16) & 1u);
    return (unsigned short)(u >> 16);
}
__device__ inline float bf2f(unsigned short b) {
    unsigned u = ((unsigned)b) << 16;
    return __builtin_bit_cast(float, u);
}

// ---------- fused prep: cast x AND transpose both weights (1 launch) ------
constexpr int PREP_CAST_BLK = 2048;
constexpr int PREP_TQ_BLK   = (QKV_N / 32) * (HID / 32);   // 12288
constexpr int PREP_TW_BLK   = (HID / 32) * (HID / 32);     // 4096

__global__ __launch_bounds__(256) void prep_kernel(
        const float* __restrict__ x, const float* __restrict__ w_qkv,
        const float* __restrict__ w_out,
        unsigned short* __restrict__ xb, unsigned short* __restrict__ wqkvT,
        unsigned short* __restrict__ woutT) {
    __shared__ float tile[32][33];
    const int b = blockIdx.x;
    if (b < PREP_CAST_BLK) {
        size_t n4 = (size_t)ROWS * HID / 4;
        size_t i = b * (size_t)blockDim.x + threadIdx.x;
        size_t stride = (size_t)PREP_CAST_BLK * blockDim.x;
        for (; i < n4; i += stride) {
            float4 v = reinterpret_cast<const float4*>(x)[i];
            ushort4 o;
            o.x = f2bf(v.x); o.y = f2bf(v.y); o.z = f2bf(v.z); o.w = f2bf(v.w);
            reinterpret_cast<ushort4*>(xb)[i] = o;
        }
        return;
    }
    const float* in;
    unsigned short* out;
    int R, Cn, tb;
    if (b < PREP_CAST_BLK + PREP_TQ_BLK) {
        tb = b - PREP_CAST_BLK; in = w_qkv; out = wqkvT; R = HID; Cn = QKV_N;
    } else {
        tb = b - PREP_CAST_BLK - PREP_TQ_BLK; in = w_out; out = woutT; R = HID; Cn = HID;
    }
    const int nbx = Cn / 32;
    const int c0 = (tb % nbx) * 32, r0 = (tb / nbx) * 32;
    const int c  = threadIdx.x & 31;
    const int r8 = threadIdx.x >> 5;          // 0..7
    #pragma unroll
    for (int i = 0; i < 32; i += 8)
        tile[r8 + i][c] = in[(size_t)(r0 + r8 + i) * Cn + c0 + c];
    __syncthreads();
    #pragma unroll
    for (int i = 0; i < 32; i += 8)
        out[(size_t)(c0 + r8 + i) * R + r0 + c] = f2bf(tile[c][r8 + i]);
}

// ====== 128x128 4-wave BK=64 double-buffered GEMM, 2 blocks/CU =============
// Final config (r10/r14/r15/r17, reproduced 4x): 191 µs GEMM1, MfmaUtil
// 52-53%, FETCH 197 MB, conflicts 0. XCD 2D-window mapping + 2 barrier
// domains. Full mapped neighborhood (all worse): 8-phase 1-blk (r4-r8),
// 8-wave same-domain (r11), BK=32 (r12/r16), B-direct (r13), fat-wave (r16).

__device__ __forceinline__ void gll(const unsigned short* src, unsigned short* dst) {
    __builtin_amdgcn_global_load_lds(
        (const __attribute__((address_space(1))) void*)src,
        (__attribute__((address_space(3))) void*)dst, 16, 0, 0);
}

// Stage one 128x64 bf16 tile (16 KB): 4 waves x 4 rounds x 8 rows.
__device__ __forceinline__ void stage_t(const unsigned short* G, int K, int k0,
                                        unsigned short* lds, int wid, int lane) {
    const int rbase = wid * 32;
    const int rl = lane >> 3;                        // 0..7 row within group
    const int ce = ((lane & 7) ^ rl) * 8;            // inverse-swizzled col
    #pragma unroll
    for (int j = 0; j < 4; ++j) {
        gll(G + (size_t)(rbase + j * 8 + rl) * K + k0 + ce,
            lds + (rbase + j * 8) * 64);
    }
}

// swizzled ds_read: row r, k-slot kk*4+fq (8 slots of 8 bf16 across BK=64)
__device__ __forceinline__ bf16x8 ld_frag(const unsigned short* tile,
                                          int r, int kk, int fq) {
    int slot = (kk * 4 + fq) ^ (r & 7);
    return *reinterpret_cast<const bf16x8*>(tile + r * 64 + slot * 8);
}

template <typename OUT_T>
__global__ __launch_bounds__(256, 2) void gemm128(
        const unsigned short* __restrict__ A,   // [M][K] bf16
        const unsigned short* __restrict__ Bt,  // [N][K] bf16
        OUT_T* __restrict__ C,                  // [M][N]
        int M, int N, int K, int byc) {
    __shared__ unsigned short As0[128 * 64];
    __shared__ unsigned short As1[128 * 64];
    __shared__ unsigned short Bs0[128 * 64];
    __shared__ unsigned short Bs1[128 * 64];

    const int bid = blockIdx.x;
    const int xcd = bid & 7;
    const int c   = bid >> 3;
    const int by  = xcd * byc + (c % byc);   // byc-wide by-band per XCD
    const int bx  = c / byc;                 // column-major within band
    const int tid = threadIdx.x, wid = tid >> 6, lane = tid & 63;
    const int wm  = wid >> 1, wn = wid & 1;         // 2x2 waves, 64x64 each
    const int fr  = lane & 15, fq = lane >> 4;

    const unsigned short* Ag = A  + (size_t)by * 128 * K;
    const unsigned short* Bg = Bt + (size_t)bx * 128 * K;

    f32x4 acc[4][4] = {};

    stage_t(Ag, K, 0, As0, wid, lane);
    stage_t(Bg, K, 0, Bs0, wid, lane);
    __syncthreads();

    const int NK = K / 64;
    for (int t = 0; t < NK; ++t) {
        const unsigned short* Ac = (t & 1) ? As1 : As0;
        const unsigned short* Bc = (t & 1) ? Bs1 : Bs0;
        if (t + 1 < NK) {   // prefetch next K-tile into the other buffer
            unsigned short* An = (t & 1) ? As0 : As1;
            unsigned short* Bn = (t & 1) ? Bs0 : Bs1;
            stage_t(Ag, K, (t + 1) * 64, An, wid, lane);
            stage_t(Bg, K, (t + 1) * 64, Bn, wid, lane);
        }
        bf16x8 af[4][2], bf[4][2];
        #pragma unroll
        for (int m = 0; m < 4; ++m) {
            int r = wm * 64 + m * 16 + fr;
            af[m][0] = ld_frag(Ac, r, 0, fq);
            af[m][1] = ld_frag(Ac, r, 1, fq);
        }
        #pragma unroll
        for (int n = 0; n < 4; ++n) {
            int r = wn * 64 + n * 16 + fr;
            bf[n][0] = ld_frag(Bc, r, 0, fq);
            bf[n][1] = ld_frag(Bc, r, 1, fq);
        }
        __builtin_amdgcn_s_setprio(1);
        #pragma unroll
        for (int kk = 0; kk < 2; ++kk)
            #pragma unroll
            for (int m = 0; m < 4; ++m)
                #pragma unroll
                for (int n = 0; n < 4; ++n)
                    acc[m][n] = __builtin_amdgcn_mfma_f32_16x16x32_bf16(
                        af[m][kk], bf[n][kk], acc[m][n], 0, 0, 0);
        __builtin_amdgcn_s_setprio(0);
        __syncthreads();
    }

    // C write (verified C/D layout: row = fq*4+r, col = fr)
    const int bm = by * 128, bn = bx * 128;
    #pragma unroll
    for (int m = 0; m < 4; ++m) {
        #pragma unroll
        for (int n = 0; n < 4; ++n) {
            #pragma unroll
            for (int r = 0; r < 4; ++r) {
                int row = bm + wm * 64 + m * 16 + fq * 4 + r;
                int col = bn + wn * 64 + n * 16 + fr;
                float v = acc[m][n][r];
                if constexpr (sizeof(OUT_T) == 2)
                    C[(size_t)row * N + col] = (OUT_T)f2bf(v);
                else
                    C[(size_t)row * N + col] = (OUT_T)v;
            }
        }
    }
}

// ---------------- scan helpers ----------------
__device__ inline float phi_f(float z) { return z > 0.f ? z + 1.f : __expf(z); }
__device__ inline float sigmoid_f(float z) { return 1.f / (1.f + __expf(-z)); }

// Pass 1: per-(b,h,chunk) local scan finals (zero init). qkv bf16.
// CHUNK=32 -> 4096 blocks (16 waves/CU): measured optimum (r15).
__global__ void scan_pass1(const unsigned short* __restrict__ qkv,
                           const float* __restrict__ decay_param,
                           float* __restrict__ fkv, float* __restrict__ fk) {
    const int blk = blockIdx.x;
    const int c = blk % NCH;
    const int h = (blk / NCH) % NH;
    const int b = blk / (NCH * NH);
    const int lane = threadIdx.x;
    const float dec = sigmoid_f(decay_param[h]);

    float skv0 = 0.f, skv1 = 0.f, sk0 = 0.f, sk1 = 0.f;
    const unsigned short* base =
        qkv + ((size_t)b * NT + (size_t)c * CHUNK) * QKV_N + h * ND;
    for (int t = 0; t < CHUNK; ++t) {
        const unsigned short* r = base + (size_t)t * QKV_N;
        unsigned kp = *reinterpret_cast<const unsigned*>(r + HID + 2 * lane);
        unsigned vp = *reinterpret_cast<const unsigned*>(r + 2 * HID + 2 * lane);
        float k0 = phi_f(bf2f((unsigned short)(kp & 0xffff)));
        float k1 = phi_f(bf2f((unsigned short)(kp >> 16)));
        float v0 = bf2f((unsigned short)(vp & 0xffff));
        float v1 = bf2f((unsigned short)(vp >> 16));
        skv0 = fmaf(dec, skv0, k0 * v0);
        skv1 = fmaf(dec, skv1, k1 * v1);
        sk0  = fmaf(dec, sk0,  k0);
        sk1  = fmaf(dec, sk1,  k1);
    }
    size_t o = (size_t)blk * ND + 2 * lane;
    *reinterpret_cast<float2*>(&fkv[o]) = make_float2(skv0, skv1);
    *reinterpret_cast<float2*>(&fk[o])  = make_float2(sk0, sk1);
}

// Pass 2: sequential chunk combine; emits carry-ins and final states.
__global__ void scan_pass2(const float* __restrict__ fkv, const float* __restrict__ fk,
                           const float* __restrict__ decay_param,
                           float* __restrict__ ckv, float* __restrict__ ck,
                           float* __restrict__ out_states) {
    const int bh = blockIdx.x;
    const int h = bh % NH;
    const int lane = threadIdx.x;
    const float dec = sigmoid_f(decay_param[h]);
    const float dL = powf(dec, (float)CHUNK);

    float Skv0 = 0.f, Skv1 = 0.f, Sk0 = 0.f, Sk1 = 0.f;
    for (int c = 0; c < NCH; ++c) {
        size_t o = ((size_t)bh * NCH + c) * ND + 2 * lane;
        *reinterpret_cast<float2*>(&ckv[o]) = make_float2(Skv0, Skv1);
        *reinterpret_cast<float2*>(&ck[o])  = make_float2(Sk0, Sk1);
        float2 fv = *reinterpret_cast<const float2*>(&fkv[o]);
        float2 fs = *reinterpret_cast<const float2*>(&fk[o]);
        Skv0 = fmaf(dL, Skv0, fv.x);
        Skv1 = fmaf(dL, Skv1, fv.y);
        Sk0  = fmaf(dL, Sk0,  fs.x);
        Sk1  = fmaf(dL, Sk1,  fs.y);
    }
    size_t so = (size_t)bh * ND + 2 * lane;
    *reinterpret_cast<float2*>(&out_states[so]) = make_float2(Skv0, Skv1);
    *reinterpret_cast<float2*>(&out_states[NB * NH * ND + so]) = make_float2(Sk0, Sk1);
}

// Pass 3: replay with carry-in; writes attn in bf16.
__global__ void scan_pass3(const unsigned short* __restrict__ qkv,
                           const float* __restrict__ decay_param,
                           const float* __restrict__ ckv, const float* __restrict__ ck,
                           unsigned short* __restrict__ attn) {
    const int blk = blockIdx.x;
    const int c = blk % NCH;
    const int h = (blk / NCH) % NH;
    const int b = blk / (NCH * NH);
    const int lane = threadIdx.x;
    const float dec = sigmoid_f(decay_param[h]);

    size_t co = (size_t)blk * ND + 2 * lane;
    float2 cv = *reinterpret_cast<const float2*>(&ckv[co]);
    float2 cs = *reinterpret_cast<const float2*>(&ck[co]);
    float skv0 = cv.x, skv1 = cv.y, sk0 = cs.x, sk1 = cs.y;

    const unsigned short* base =
        qkv + ((size_t)b * NT + (size_t)c * CHUNK) * QKV_N + h * ND;
    unsigned short* abase =
        attn + ((size_t)b * NT + (size_t)c * CHUNK) * HID + h * ND;

    for (int t = 0; t < CHUNK; ++t) {
        const unsigned short* r = base + (size_t)t * QKV_N;
        unsigned qp = *reinterpret_cast<const unsigned*>(r + 2 * lane);
        unsigned kp = *reinterpret_cast<const unsigned*>(r + HID + 2 * lane);
        unsigned vp = *reinterpret_cast<const unsigned*>(r + 2 * HID + 2 * lane);
        float q0 = phi_f(bf2f((unsigned short)(qp & 0xffff)));
        float q1 = phi_f(bf2f((unsigned short)(qp >> 16)));
        float k0 = phi_f(bf2f((unsigned short)(kp & 0xffff)));
        float k1 = phi_f(bf2f((unsigned short)(kp >> 16)));
        float v0 = bf2f((unsigned short)(vp & 0xffff));
        float v1 = bf2f((unsigned short)(vp >> 16));
        skv0 = fmaf(dec, skv0, k0 * v0);
        skv1 = fmaf(dec, skv1, k1 * v1);
        sk0  = fmaf(dec, sk0,  k0);
        sk1  = fmaf(dec, sk1,  k1);
        float den = fmaf(q0, sk0, q1 * sk1);
        #pragma unroll
        for (int m = 1; m < 64; m <<= 1) den += __shfl_xor(den, m, 64);
        den = fmaxf(den, 1e-6f);
        float inv = 1.f / den;
        unsigned o = ((unsigned)f2bf(q1 * skv1 * inv) << 16) |
                     (unsigned)f2bf(q0 * skv0 * inv);
        *reinterpret_cast<unsigned*>(abase + (size_t)t * HID + 2 * lane) = o;
    }
}

// ---------------- launch ----------------
extern "C" void kernel_launch(void* const* d_in, const int* in_sizes, int n_in,
                              void* d_out, int out_size, void* d_ws, size_t ws_size,
                              hipStream_t stream) {
    const float* x      = (const float*)d_in[0];   // [2,4096,2048]
    const float* w_qkv  = (const float*)d_in[1];   // [2048,6144]
    const float* w_out  = (const float*)d_in[2];   // [2048,2048]
    const float* decayp = (const float*)d_in[3];   // [16]
    float* out = (float*)d_out;

    // workspace layout
    char* ws = (char*)d_ws;
    unsigned short* xb     = (unsigned short*)ws;                         // 8192*2048
    unsigned short* wqkvT  = xb    + (size_t)ROWS * HID;                  // 6144*2048
    unsigned short* woutT  = wqkvT + (size_t)QKV_N * HID;                 // 2048*2048
    unsigned short* qkvb   = woutT + (size_t)HID * HID;                   // 8192*6144
    unsigned short* attnb  = qkvb  + (size_t)ROWS * QKV_N;                // 8192*2048
    float* fkv = (float*)(attnb + (size_t)ROWS * HID);
    float* fk  = fkv + (size_t)NB * NH * NCH * ND;
    float* ckv = fk  + (size_t)NB * NH * NCH * ND;
    float* ck  = ckv + (size_t)NB * NH * NCH * ND;

    // fused prep: cast x + transpose both weights (1 launch)
    prep_kernel<<<PREP_CAST_BLK + PREP_TQ_BLK + PREP_TW_BLK, 256, 0, stream>>>(
        x, w_qkv, w_out, xb, wqkvT, woutT);

    // GEMM1: qkvb = xb @ wqkvT^T   (bf16 out)  grid 64x48 = 3072 blocks
    {
        int nby = ROWS / 128, nbx = QKV_N / 128;
        gemm128<unsigned short><<<nby * nbx, 256, 0, stream>>>(
            xb, wqkvT, qkvb, ROWS, QKV_N, HID, nby / 8);
    }

    // chunked decay scans (CHUNK=32 -> 4096 blocks, measured optimum)
    scan_pass1<<<NB * NH * NCH, 64, 0, stream>>>(qkvb, decayp, fkv, fk);
    scan_pass2<<<NB * NH, 64, 0, stream>>>(fkv, fk, decayp, ckv, ck,
                                           out + (size_t)ROWS * HID);
    scan_pass3<<<NB * NH * NCH, 64, 0, stream>>>(qkvb, decayp, ckv, ck, attnb);

    // GEMM2: out = attnb @ woutT^T  (f32 out)  grid 64x16 = 1024 blocks
    {
        int nby = ROWS / 128, nbx = HID / 128;
        gemm128<float><<<nby * nbx, 256, 0, stream>>>(
            attnb, woutT, out, ROWS, HID, HID, nby / 8);
    }
}